// Round 6
// baseline (64.914 us; speedup 1.0000x reference)
//
#include <hip/hip_runtime.h>
#include <math.h>

// Forward kinematics, 6-joint DH chain, B=1048576.
// R6: two-kernel split.
//   fk6_fast : pure-f32 chain, launch_bounds(256,8) -> VGPR<=64, high occupancy.
//              Risky lanes (atan2 branch-cut / gimbal decisions within ~50x of
//              f32 noise) append their index into d_ws.
//   fk6_fix  : small fixed-grid kernel; recomputes flagged indices with the
//              exact f64 path that passed R3-R5 (overwrites f32 result).
// Fallback: if ws_size is tiny, launch the R5 single-kernel version.

#define PI_D   3.141592653589793
#define RAD_D  (PI_D / 180.0)
#define RAD_F  0.017453292519943295f
#define DEG_F  57.29577951308232f
#define TINY_D 1e-6

// ---------- f64 sincos of degrees (Cephes, ~1ulp) ----------
__device__ __forceinline__ void sincos_deg(double xdeg, double* s, double* c)
{
    const double qf = rint(xdeg * (1.0 / 90.0));
    const double r  = fma(qf, -90.0, xdeg) * RAD_D;
    const int q = ((int)qf) & 3;
    const double z = r * r;

    double sp = 1.58962301576546568060e-10;
    sp = fma(sp, z, -2.50507477628578072866e-8);
    sp = fma(sp, z,  2.75573136213857245213e-6);
    sp = fma(sp, z, -1.98412698295895385996e-4);
    sp = fma(sp, z,  8.33333333332211858878e-3);
    sp = fma(sp, z, -1.66666666666666307295e-1);
    const double sr = fma(r * z, sp, r);

    double cp = -1.13585365213876817300e-11;
    cp = fma(cp, z,  2.08757008419747316778e-9);
    cp = fma(cp, z, -2.75573141792967388112e-7);
    cp = fma(cp, z,  2.48015872888517179954e-5);
    cp = fma(cp, z, -1.38888888888730564116e-3);
    cp = fma(cp, z,  4.16666666666665929218e-2);
    const double cr = fma(z * z, cp, fma(z, -0.5, 1.0));

    double ss = (q & 1) ? cr : sr;
    double cc = (q & 1) ? sr : cr;
    ss = (q & 2)       ? -ss : ss;
    cc = ((q + 1) & 2) ? -cc : cc;
    *s = ss; *c = cc;
}

// ---------- f32 sincos of degrees (Cephes f32, ~1ulp f32) ----------
__device__ __forceinline__ void sincosf_deg(float xdeg, float* s, float* c)
{
    const float qf = rintf(xdeg * (1.0f / 90.0f));
    const float r  = fmaf(qf, -90.0f, xdeg) * RAD_F;
    const int q = ((int)qf) & 3;
    const float z = r * r;

    float sp = -1.9515295891e-4f;
    sp = fmaf(sp, z,  8.3321608736e-3f);
    sp = fmaf(sp, z, -1.6666654611e-1f);
    const float sr = fmaf(r * z, sp, r);

    float cp =  2.443315711809948e-5f;
    cp = fmaf(cp, z, -1.388731625493765e-3f);
    cp = fmaf(cp, z,  4.166664568298827e-2f);
    const float cr = fmaf(z * z, cp, fmaf(z, -0.5f, 1.0f));

    float ss = (q & 1) ? cr : sr;
    float cc = (q & 1) ? sr : cr;
    ss = (q & 2)       ? -ss : ss;
    cc = ((q + 1) & 2) ? -cc : cc;
    *s = ss; *c = cc;
}

// ===================== fast kernel: pure f32 =====================
__global__ __launch_bounds__(256, 8)
void fk6_fast(const float* __restrict__ theta,
              const float* __restrict__ dh,
              float* __restrict__ out,
              unsigned* __restrict__ risk_cnt,
              unsigned* __restrict__ risk_idx,
              unsigned cap,
              int B)
{
    __shared__ float f_a[6], f_ca[6], f_sa[6], f_nsd[6], f_cd[6], f_th0[6];
    if (threadIdx.x < 6) {
        const int i = threadIdx.x;
        const float a   = dh[i * 4 + 0];
        const float alp = dh[i * 4 + 1];
        const float d   = dh[i * 4 + 2];
        float sa, ca;
        sincosf_deg(alp, &sa, &ca);   // exact for multiples of 90 deg
        f_a[i] = a;  f_ca[i] = ca;  f_sa[i] = sa;
        f_nsd[i] = -sa * d;  f_cd[i] = ca * d;
        f_th0[i] = dh[i * 4 + 3];
    }
    __syncthreads();

    const long long b = (long long)blockIdx.x * blockDim.x + threadIdx.x;
    if (b >= B) return;

    const float2* tp = reinterpret_cast<const float2*>(theta + 6ll * b);
    const float2 v01 = tp[0];
    const float2 v23 = tp[1];
    const float2 v45 = tp[2];
    const float thf[6] = { v01.x, v01.y, v23.x, v23.y, v45.x, v45.y };

    float st[6], ct[6];
    #pragma unroll
    for (int i = 0; i < 6; ++i)
        sincosf_deg(f_th0[i] + thf[i], &st[i], &ct[i]);

    float M[3][4];
    {
        const float ca = f_ca[0], sa = f_sa[0];
        M[0][0] = ct[0];      M[0][1] = -st[0];     M[0][2] = 0.0f; M[0][3] = f_a[0];
        M[1][0] = st[0] * ca; M[1][1] = ct[0] * ca; M[1][2] = -sa;  M[1][3] = f_nsd[0];
        M[2][0] = st[0] * sa; M[2][1] = ct[0] * sa; M[2][2] = ca;   M[2][3] = f_cd[0];
    }
    #pragma unroll
    for (int i = 1; i < 6; ++i) {
        const float ca = f_ca[i], sa = f_sa[i];
        const float t00 = ct[i],      t01 = -st[i],     t03 = f_a[i];
        const float t10 = st[i] * ca, t11 = ct[i] * ca, t12 = -sa, t13 = f_nsd[i];
        const float t20 = st[i] * sa, t21 = ct[i] * sa, t22 = ca,  t23 = f_cd[i];
        #pragma unroll
        for (int r = 0; r < 3; ++r) {
            const float m0 = M[r][0], m1 = M[r][1], m2 = M[r][2], m3 = M[r][3];
            M[r][0] = m0 * t00 + m1 * t10 + m2 * t20;
            M[r][1] = m0 * t01 + m1 * t11 + m2 * t21;
            M[r][2] =            m1 * t12 + m2 * t22;         // t02 == 0
            M[r][3] = m0 * t03 + m1 * t13 + m2 * t23 + m3;    // t33 == 1
        }
    }

    const float T00 = M[0][0], T01 = M[0][1], T02 = M[0][2];
    const float T12 = M[1][2], T22 = M[2][2];

    const float A  = atan2f(-T01, T00) * DEG_F;
    // cA*T00 - sA*T01 == sqrt(T00^2+T01^2) >= 0 (unit row) -> no branch cut.
    const float Bd = atan2f(T02, sqrtf(fmaf(T00, T00, T01 * T01))) * DEG_F;
    const float C  = atan2f(-T12, T22) * DEG_F;

    float2* op = reinterpret_cast<float2*>(out + 6ll * b);
    op[0] = make_float2(M[0][3], M[1][3]);
    op[1] = make_float2(M[2][3], A);
    op[2] = make_float2(Bd, C);

    // Flag lanes whose sign/branch decisions sit within ~50x of f32 noise.
    const bool risky = (fabsf(T01) < 1e-4f) | (fabsf(T12) < 1e-4f) |
                       (fmaf(T00, T00, T01 * T01) < 1e-6f) |
                       (fmaf(T12, T12, T22 * T22) < 1e-6f);
    if (__builtin_expect(risky, 0)) {
        const unsigned idx = atomicAdd(risk_cnt, 1u);
        if (idx < cap) risk_idx[idx] = (unsigned)b;
    }
}

// ===================== fixup kernel: exact f64 path =====================
__global__ void fk6_fix(const float* __restrict__ theta,
                        const float* __restrict__ dh,
                        float* __restrict__ out,
                        const unsigned* __restrict__ risk_cnt,
                        const unsigned* __restrict__ risk_idx,
                        unsigned cap)
{
    __shared__ double s_a[6], s_ca[6], s_sa[6], s_nsd[6], s_cd[6], s_th0[6];
    if (threadIdx.x < 6) {
        const int i = threadIdx.x;
        const double a   = (double)dh[i * 4 + 0];
        const double alp = (double)dh[i * 4 + 1];
        const double d   = (double)dh[i * 4 + 2];
        double sa, ca;
        sincos_deg(alp, &sa, &ca);
        s_a[i] = a;  s_ca[i] = ca;  s_sa[i] = sa;
        s_nsd[i] = -sa * d;  s_cd[i] = ca * d;
        s_th0[i] = (double)dh[i * 4 + 3];
    }
    __syncthreads();

    unsigned n = *risk_cnt;
    if (n > cap) n = cap;

    for (unsigned t = blockIdx.x * blockDim.x + threadIdx.x; t < n;
         t += gridDim.x * blockDim.x) {
        const long long b = (long long)risk_idx[t];
        const float2* tp = reinterpret_cast<const float2*>(theta + 6ll * b);
        const float2 v01 = tp[0];
        const float2 v23 = tp[1];
        const float2 v45 = tp[2];
        const double th[6] = { (double)v01.x, (double)v01.y,
                               (double)v23.x, (double)v23.y,
                               (double)v45.x, (double)v45.y };

        double dst[6], dct[6];
        #pragma unroll
        for (int i = 0; i < 6; ++i)
            sincos_deg(s_th0[i] + th[i], &dst[i], &dct[i]);

        double D[3][4];
        {
            const double ca = s_ca[0], sa = s_sa[0];
            D[0][0] = dct[0];      D[0][1] = -dst[0];     D[0][2] = 0.0; D[0][3] = s_a[0];
            D[1][0] = dst[0] * ca; D[1][1] = dct[0] * ca; D[1][2] = -sa; D[1][3] = s_nsd[0];
            D[2][0] = dst[0] * sa; D[2][1] = dct[0] * sa; D[2][2] = ca;  D[2][3] = s_cd[0];
        }
        #pragma unroll
        for (int i = 1; i < 6; ++i) {
            const double ca = s_ca[i], sa = s_sa[i];
            const double t00 = dct[i],      t01 = -dst[i],     t03 = s_a[i];
            const double t10 = dst[i] * ca, t11 = dct[i] * ca, t12 = -sa, t13 = s_nsd[i];
            const double t20 = dst[i] * sa, t21 = dct[i] * sa, t22 = ca,  t23 = s_cd[i];
            #pragma unroll
            for (int r = 0; r < 3; ++r) {
                const double m0 = D[r][0], m1 = D[r][1], m2 = D[r][2], m3 = D[r][3];
                D[r][0] = m0 * t00 + m1 * t10 + m2 * t20;
                D[r][1] = m0 * t01 + m1 * t11 + m2 * t21;
                D[r][2] =            m1 * t12 + m2 * t22;
                D[r][3] = m0 * t03 + m1 * t13 + m2 * t23 + m3;
            }
        }
        const float d00 = (float)D[0][0], d01 = (float)D[0][1], d02 = (float)D[0][2];
        const float d12 = (float)D[1][2], d22 = (float)D[2][2];

        float A  = atan2f(-d01, d00) * DEG_F;
        float Bd = atan2f(d02, sqrtf(fmaf(d00, d00, d01 * d01))) * DEG_F;
        float C  = atan2f(-d12, d22) * DEG_F;
        if (fabs(D[1][2]) <= TINY_D && fabs(D[2][2]) <= TINY_D) {
            Bd = atan2f(d02, d22) * DEG_F;
            A  = atan2f((float)D[1][0], (float)D[1][1]) * DEG_F;
            C  = 0.0f;
        }

        float2* op = reinterpret_cast<float2*>(out + 6ll * b);
        op[0] = make_float2((float)D[0][3], (float)D[1][3]);
        op[1] = make_float2((float)D[2][3], A);
        op[2] = make_float2(Bd, C);
    }
}

// ===================== fallback: R5 combined kernel =====================
__global__ __launch_bounds__(256)
void fk6_combined(const float* __restrict__ theta,
                  const float* __restrict__ dh,
                  float* __restrict__ out,
                  int B)
{
    __shared__ double s_a[6], s_ca[6], s_sa[6], s_nsd[6], s_cd[6], s_th0[6];
    __shared__ float  f_a[6], f_ca[6], f_sa[6], f_nsd[6], f_cd[6], f_th0[6];
    if (threadIdx.x < 6) {
        const int i = threadIdx.x;
        const double a   = (double)dh[i * 4 + 0];
        const double alp = (double)dh[i * 4 + 1];
        const double d   = (double)dh[i * 4 + 2];
        const double th0 = (double)dh[i * 4 + 3];
        double sa, ca;
        sincos_deg(alp, &sa, &ca);
        s_a[i] = a;  s_ca[i] = ca;  s_sa[i] = sa;
        s_nsd[i] = -sa * d;  s_cd[i] = ca * d;  s_th0[i] = th0;
        f_a[i] = (float)a;  f_ca[i] = (float)ca;  f_sa[i] = (float)sa;
        f_nsd[i] = (float)(-sa * d);  f_cd[i] = (float)(ca * d);  f_th0[i] = (float)th0;
    }
    __syncthreads();

    const long long b = (long long)blockIdx.x * blockDim.x + threadIdx.x;
    if (b >= B) return;

    const float2* tp = reinterpret_cast<const float2*>(theta + 6ll * b);
    const float2 v01 = tp[0];
    const float2 v23 = tp[1];
    const float2 v45 = tp[2];
    const float thf[6] = { v01.x, v01.y, v23.x, v23.y, v45.x, v45.y };

    float st[6], ct[6];
    #pragma unroll
    for (int i = 0; i < 6; ++i)
        sincosf_deg(f_th0[i] + thf[i], &st[i], &ct[i]);

    float M[3][4];
    {
        const float ca = f_ca[0], sa = f_sa[0];
        M[0][0] = ct[0];      M[0][1] = -st[0];     M[0][2] = 0.0f; M[0][3] = f_a[0];
        M[1][0] = st[0] * ca; M[1][1] = ct[0] * ca; M[1][2] = -sa;  M[1][3] = f_nsd[0];
        M[2][0] = st[0] * sa; M[2][1] = ct[0] * sa; M[2][2] = ca;   M[2][3] = f_cd[0];
    }
    #pragma unroll
    for (int i = 1; i < 6; ++i) {
        const float ca = f_ca[i], sa = f_sa[i];
        const float t00 = ct[i],      t01 = -st[i],     t03 = f_a[i];
        const float t10 = st[i] * ca, t11 = ct[i] * ca, t12 = -sa, t13 = f_nsd[i];
        const float t20 = st[i] * sa, t21 = ct[i] * sa, t22 = ca,  t23 = f_cd[i];
        #pragma unroll
        for (int r = 0; r < 3; ++r) {
            const float m0 = M[r][0], m1 = M[r][1], m2 = M[r][2], m3 = M[r][3];
            M[r][0] = m0 * t00 + m1 * t10 + m2 * t20;
            M[r][1] = m0 * t01 + m1 * t11 + m2 * t21;
            M[r][2] =            m1 * t12 + m2 * t22;
            M[r][3] = m0 * t03 + m1 * t13 + m2 * t23 + m3;
        }
    }

    const float T00 = M[0][0], T01 = M[0][1], T02 = M[0][2];
    const float T12 = M[1][2], T22 = M[2][2];

    float ox = M[0][3], oy = M[1][3], oz = M[2][3];
    float A  = atan2f(-T01, T00) * DEG_F;
    float Bd = atan2f(T02, sqrtf(fmaf(T00, T00, T01 * T01))) * DEG_F;
    float C  = atan2f(-T12, T22) * DEG_F;

    const bool risky = (fabsf(T01) < 1e-4f) | (fabsf(T12) < 1e-4f) |
                       (fmaf(T00, T00, T01 * T01) < 1e-6f) |
                       (fmaf(T12, T12, T22 * T22) < 1e-6f);

    if (__builtin_expect(risky, 0)) {
        double dst[6], dct[6];
        #pragma unroll
        for (int i = 0; i < 6; ++i)
            sincos_deg(s_th0[i] + (double)thf[i], &dst[i], &dct[i]);

        double D[3][4];
        {
            const double ca = s_ca[0], sa = s_sa[0];
            D[0][0] = dct[0];      D[0][1] = -dst[0];     D[0][2] = 0.0; D[0][3] = s_a[0];
            D[1][0] = dst[0] * ca; D[1][1] = dct[0] * ca; D[1][2] = -sa; D[1][3] = s_nsd[0];
            D[2][0] = dst[0] * sa; D[2][1] = dct[0] * sa; D[2][2] = ca;  D[2][3] = s_cd[0];
        }
        #pragma unroll
        for (int i = 1; i < 6; ++i) {
            const double ca = s_ca[i], sa = s_sa[i];
            const double t00 = dct[i],      t01 = -dst[i],     t03 = s_a[i];
            const double t10 = dst[i] * ca, t11 = dct[i] * ca, t12 = -sa, t13 = s_nsd[i];
            const double t20 = dst[i] * sa, t21 = dct[i] * sa, t22 = ca,  t23 = s_cd[i];
            #pragma unroll
            for (int r = 0; r < 3; ++r) {
                const double m0 = D[r][0], m1 = D[r][1], m2 = D[r][2], m3 = D[r][3];
                D[r][0] = m0 * t00 + m1 * t10 + m2 * t20;
                D[r][1] = m0 * t01 + m1 * t11 + m2 * t21;
                D[r][2] =            m1 * t12 + m2 * t22;
                D[r][3] = m0 * t03 + m1 * t13 + m2 * t23 + m3;
            }
        }
        const float d00 = (float)D[0][0], d01 = (float)D[0][1], d02 = (float)D[0][2];
        const float d12 = (float)D[1][2], d22 = (float)D[2][2];

        ox = (float)D[0][3]; oy = (float)D[1][3]; oz = (float)D[2][3];
        A  = atan2f(-d01, d00) * DEG_F;
        Bd = atan2f(d02, sqrtf(fmaf(d00, d00, d01 * d01))) * DEG_F;
        C  = atan2f(-d12, d22) * DEG_F;
        if (fabs(D[1][2]) <= TINY_D && fabs(D[2][2]) <= TINY_D) {
            Bd = atan2f(d02, d22) * DEG_F;
            A  = atan2f((float)D[1][0], (float)D[1][1]) * DEG_F;
            C  = 0.0f;
        }
    }

    float2* op = reinterpret_cast<float2*>(out + 6ll * b);
    op[0] = make_float2(ox, oy);
    op[1] = make_float2(oz, A);
    op[2] = make_float2(Bd, C);
}

extern "C" void kernel_launch(void* const* d_in, const int* in_sizes, int n_in,
                              void* d_out, int out_size, void* d_ws, size_t ws_size,
                              hipStream_t stream) {
    const float* theta = (const float*)d_in[0];   // (B, 6) f32
    const float* dh    = (const float*)d_in[1];   // (6, 4) f32
    float* out = (float*)d_out;                   // (B, 6) f32

    const int B = in_sizes[0] / 6;
    const int block = 256;
    const int grid = (B + block - 1) / block;

    if (ws_size >= 65536) {
        unsigned* risk_cnt = (unsigned*)d_ws;
        unsigned* risk_idx = (unsigned*)((char*)d_ws + 256);
        const unsigned cap = (unsigned)((ws_size - 256) / 4);
        hipMemsetAsync(d_ws, 0, 4, stream);   // zero the counter (capturable)
        fk6_fast<<<grid, block, 0, stream>>>(theta, dh, out,
                                             risk_cnt, risk_idx, cap, B);
        fk6_fix<<<16, 256, 0, stream>>>(theta, dh, out, risk_cnt, risk_idx, cap);
    } else {
        fk6_combined<<<grid, block, 0, stream>>>(theta, dh, out, B);
    }
}

// Round 7
// 34.360 us; speedup vs baseline: 1.8892x; 1.8892x over previous
//
#include <hip/hip_runtime.h>
#include <math.h>

// Forward kinematics, 6-joint DH chain, B=1048576.
// R7: two-kernel split, spill-free.
//   fk6_fast : pure-f32 chain, launch_bounds(256,4) (<=128 VGPR cap — R6's
//              (256,8) forced VGPR=32 and spilled ~170MB to scratch).
//              Risky lanes append their index into d_ws.
//   fk6_fix  : small fixed-grid kernel; recomputes flagged indices with the
//              exact f64 path that passed R3-R5.
// Fallback: single combined kernel if ws_size is tiny.

#define PI_D   3.141592653589793
#define RAD_D  (PI_D / 180.0)
#define RAD_F  0.017453292519943295f
#define DEG_F  57.29577951308232f
#define TINY_D 1e-6

// ---------- f64 sincos of degrees (Cephes, ~1ulp) ----------
__device__ __forceinline__ void sincos_deg(double xdeg, double* s, double* c)
{
    const double qf = rint(xdeg * (1.0 / 90.0));
    const double r  = fma(qf, -90.0, xdeg) * RAD_D;
    const int q = ((int)qf) & 3;
    const double z = r * r;

    double sp = 1.58962301576546568060e-10;
    sp = fma(sp, z, -2.50507477628578072866e-8);
    sp = fma(sp, z,  2.75573136213857245213e-6);
    sp = fma(sp, z, -1.98412698295895385996e-4);
    sp = fma(sp, z,  8.33333333332211858878e-3);
    sp = fma(sp, z, -1.66666666666666307295e-1);
    const double sr = fma(r * z, sp, r);

    double cp = -1.13585365213876817300e-11;
    cp = fma(cp, z,  2.08757008419747316778e-9);
    cp = fma(cp, z, -2.75573141792967388112e-7);
    cp = fma(cp, z,  2.48015872888517179954e-5);
    cp = fma(cp, z, -1.38888888888730564116e-3);
    cp = fma(cp, z,  4.16666666666665929218e-2);
    const double cr = fma(z * z, cp, fma(z, -0.5, 1.0));

    double ss = (q & 1) ? cr : sr;
    double cc = (q & 1) ? sr : cr;
    ss = (q & 2)       ? -ss : ss;
    cc = ((q + 1) & 2) ? -cc : cc;
    *s = ss; *c = cc;
}

// ---------- f32 sincos of degrees (Cephes f32, ~1ulp f32) ----------
__device__ __forceinline__ void sincosf_deg(float xdeg, float* s, float* c)
{
    const float qf = rintf(xdeg * (1.0f / 90.0f));
    const float r  = fmaf(qf, -90.0f, xdeg) * RAD_F;
    const int q = ((int)qf) & 3;
    const float z = r * r;

    float sp = -1.9515295891e-4f;
    sp = fmaf(sp, z,  8.3321608736e-3f);
    sp = fmaf(sp, z, -1.6666654611e-1f);
    const float sr = fmaf(r * z, sp, r);

    float cp =  2.443315711809948e-5f;
    cp = fmaf(cp, z, -1.388731625493765e-3f);
    cp = fmaf(cp, z,  4.166664568298827e-2f);
    const float cr = fmaf(z * z, cp, fmaf(z, -0.5f, 1.0f));

    float ss = (q & 1) ? cr : sr;
    float cc = (q & 1) ? sr : cr;
    ss = (q & 2)       ? -ss : ss;
    cc = ((q + 1) & 2) ? -cc : cc;
    *s = ss; *c = cc;
}

// ===================== fast kernel: pure f32 =====================
__global__ __launch_bounds__(256, 4)   // <=128 VGPR: no spill (R6 lesson)
void fk6_fast(const float* __restrict__ theta,
              const float* __restrict__ dh,
              float* __restrict__ out,
              unsigned* __restrict__ risk_cnt,
              unsigned* __restrict__ risk_idx,
              unsigned cap,
              int B)
{
    __shared__ float f_a[6], f_ca[6], f_sa[6], f_nsd[6], f_cd[6], f_th0[6];
    if (threadIdx.x < 6) {
        const int i = threadIdx.x;
        const float a   = dh[i * 4 + 0];
        const float alp = dh[i * 4 + 1];
        const float d   = dh[i * 4 + 2];
        float sa, ca;
        sincosf_deg(alp, &sa, &ca);   // exact for multiples of 90 deg
        f_a[i] = a;  f_ca[i] = ca;  f_sa[i] = sa;
        f_nsd[i] = -sa * d;  f_cd[i] = ca * d;
        f_th0[i] = dh[i * 4 + 3];
    }
    __syncthreads();

    const long long b = (long long)blockIdx.x * blockDim.x + threadIdx.x;
    if (b >= B) return;

    const float2* tp = reinterpret_cast<const float2*>(theta + 6ll * b);
    const float2 v01 = tp[0];
    const float2 v23 = tp[1];
    const float2 v45 = tp[2];
    const float thf[6] = { v01.x, v01.y, v23.x, v23.y, v45.x, v45.y };

    float st[6], ct[6];
    #pragma unroll
    for (int i = 0; i < 6; ++i)
        sincosf_deg(f_th0[i] + thf[i], &st[i], &ct[i]);

    float M[3][4];
    {
        const float ca = f_ca[0], sa = f_sa[0];
        M[0][0] = ct[0];      M[0][1] = -st[0];     M[0][2] = 0.0f; M[0][3] = f_a[0];
        M[1][0] = st[0] * ca; M[1][1] = ct[0] * ca; M[1][2] = -sa;  M[1][3] = f_nsd[0];
        M[2][0] = st[0] * sa; M[2][1] = ct[0] * sa; M[2][2] = ca;   M[2][3] = f_cd[0];
    }
    #pragma unroll
    for (int i = 1; i < 6; ++i) {
        const float ca = f_ca[i], sa = f_sa[i];
        const float t00 = ct[i],      t01 = -st[i],     t03 = f_a[i];
        const float t10 = st[i] * ca, t11 = ct[i] * ca, t12 = -sa, t13 = f_nsd[i];
        const float t20 = st[i] * sa, t21 = ct[i] * sa, t22 = ca,  t23 = f_cd[i];
        #pragma unroll
        for (int r = 0; r < 3; ++r) {
            const float m0 = M[r][0], m1 = M[r][1], m2 = M[r][2], m3 = M[r][3];
            M[r][0] = m0 * t00 + m1 * t10 + m2 * t20;
            M[r][1] = m0 * t01 + m1 * t11 + m2 * t21;
            M[r][2] =            m1 * t12 + m2 * t22;         // t02 == 0
            M[r][3] = m0 * t03 + m1 * t13 + m2 * t23 + m3;    // t33 == 1
        }
    }

    const float T00 = M[0][0], T01 = M[0][1], T02 = M[0][2];
    const float T12 = M[1][2], T22 = M[2][2];

    const float A  = atan2f(-T01, T00) * DEG_F;
    // cA*T00 - sA*T01 == sqrt(T00^2+T01^2) >= 0 (unit row) -> no branch cut.
    const float Bd = atan2f(T02, sqrtf(fmaf(T00, T00, T01 * T01))) * DEG_F;
    const float C  = atan2f(-T12, T22) * DEG_F;

    float2* op = reinterpret_cast<float2*>(out + 6ll * b);
    op[0] = make_float2(M[0][3], M[1][3]);
    op[1] = make_float2(M[2][3], A);
    op[2] = make_float2(Bd, C);

    // Flag lanes whose sign/branch decisions sit within ~50x of f32 noise.
    const bool risky = (fabsf(T01) < 1e-4f) | (fabsf(T12) < 1e-4f) |
                       (fmaf(T00, T00, T01 * T01) < 1e-6f) |
                       (fmaf(T12, T12, T22 * T22) < 1e-6f);
    if (__builtin_expect(risky, 0)) {
        const unsigned idx = atomicAdd(risk_cnt, 1u);
        if (idx < cap) risk_idx[idx] = (unsigned)b;
    }
}

// ===================== fixup kernel: exact f64 path =====================
__global__ void fk6_fix(const float* __restrict__ theta,
                        const float* __restrict__ dh,
                        float* __restrict__ out,
                        const unsigned* __restrict__ risk_cnt,
                        const unsigned* __restrict__ risk_idx,
                        unsigned cap)
{
    __shared__ double s_a[6], s_ca[6], s_sa[6], s_nsd[6], s_cd[6], s_th0[6];
    if (threadIdx.x < 6) {
        const int i = threadIdx.x;
        const double a   = (double)dh[i * 4 + 0];
        const double alp = (double)dh[i * 4 + 1];
        const double d   = (double)dh[i * 4 + 2];
        double sa, ca;
        sincos_deg(alp, &sa, &ca);
        s_a[i] = a;  s_ca[i] = ca;  s_sa[i] = sa;
        s_nsd[i] = -sa * d;  s_cd[i] = ca * d;
        s_th0[i] = (double)dh[i * 4 + 3];
    }
    __syncthreads();

    unsigned n = *risk_cnt;
    if (n > cap) n = cap;

    for (unsigned t = blockIdx.x * blockDim.x + threadIdx.x; t < n;
         t += gridDim.x * blockDim.x) {
        const long long b = (long long)risk_idx[t];
        const float2* tp = reinterpret_cast<const float2*>(theta + 6ll * b);
        const float2 v01 = tp[0];
        const float2 v23 = tp[1];
        const float2 v45 = tp[2];
        const double th[6] = { (double)v01.x, (double)v01.y,
                               (double)v23.x, (double)v23.y,
                               (double)v45.x, (double)v45.y };

        double dst[6], dct[6];
        #pragma unroll
        for (int i = 0; i < 6; ++i)
            sincos_deg(s_th0[i] + th[i], &dst[i], &dct[i]);

        double D[3][4];
        {
            const double ca = s_ca[0], sa = s_sa[0];
            D[0][0] = dct[0];      D[0][1] = -dst[0];     D[0][2] = 0.0; D[0][3] = s_a[0];
            D[1][0] = dst[0] * ca; D[1][1] = dct[0] * ca; D[1][2] = -sa; D[1][3] = s_nsd[0];
            D[2][0] = dst[0] * sa; D[2][1] = dct[0] * sa; D[2][2] = ca;  D[2][3] = s_cd[0];
        }
        #pragma unroll
        for (int i = 1; i < 6; ++i) {
            const double ca = s_ca[i], sa = s_sa[i];
            const double t00 = dct[i],      t01 = -dst[i],     t03 = s_a[i];
            const double t10 = dst[i] * ca, t11 = dct[i] * ca, t12 = -sa, t13 = s_nsd[i];
            const double t20 = dst[i] * sa, t21 = dct[i] * sa, t22 = ca,  t23 = s_cd[i];
            #pragma unroll
            for (int r = 0; r < 3; ++r) {
                const double m0 = D[r][0], m1 = D[r][1], m2 = D[r][2], m3 = D[r][3];
                D[r][0] = m0 * t00 + m1 * t10 + m2 * t20;
                D[r][1] = m0 * t01 + m1 * t11 + m2 * t21;
                D[r][2] =            m1 * t12 + m2 * t22;
                D[r][3] = m0 * t03 + m1 * t13 + m2 * t23 + m3;
            }
        }
        const float d00 = (float)D[0][0], d01 = (float)D[0][1], d02 = (float)D[0][2];
        const float d12 = (float)D[1][2], d22 = (float)D[2][2];

        float A  = atan2f(-d01, d00) * DEG_F;
        float Bd = atan2f(d02, sqrtf(fmaf(d00, d00, d01 * d01))) * DEG_F;
        float C  = atan2f(-d12, d22) * DEG_F;
        if (fabs(D[1][2]) <= TINY_D && fabs(D[2][2]) <= TINY_D) {
            Bd = atan2f(d02, d22) * DEG_F;
            A  = atan2f((float)D[1][0], (float)D[1][1]) * DEG_F;
            C  = 0.0f;
        }

        float2* op = reinterpret_cast<float2*>(out + 6ll * b);
        op[0] = make_float2((float)D[0][3], (float)D[1][3]);
        op[1] = make_float2((float)D[2][3], A);
        op[2] = make_float2(Bd, C);
    }
}

// ===================== fallback: combined kernel =====================
__global__ __launch_bounds__(256)
void fk6_combined(const float* __restrict__ theta,
                  const float* __restrict__ dh,
                  float* __restrict__ out,
                  int B)
{
    __shared__ double s_a[6], s_ca[6], s_sa[6], s_nsd[6], s_cd[6], s_th0[6];
    __shared__ float  f_a[6], f_ca[6], f_sa[6], f_nsd[6], f_cd[6], f_th0[6];
    if (threadIdx.x < 6) {
        const int i = threadIdx.x;
        const double a   = (double)dh[i * 4 + 0];
        const double alp = (double)dh[i * 4 + 1];
        const double d   = (double)dh[i * 4 + 2];
        const double th0 = (double)dh[i * 4 + 3];
        double sa, ca;
        sincos_deg(alp, &sa, &ca);
        s_a[i] = a;  s_ca[i] = ca;  s_sa[i] = sa;
        s_nsd[i] = -sa * d;  s_cd[i] = ca * d;  s_th0[i] = th0;
        f_a[i] = (float)a;  f_ca[i] = (float)ca;  f_sa[i] = (float)sa;
        f_nsd[i] = (float)(-sa * d);  f_cd[i] = (float)(ca * d);  f_th0[i] = (float)th0;
    }
    __syncthreads();

    const long long b = (long long)blockIdx.x * blockDim.x + threadIdx.x;
    if (b >= B) return;

    const float2* tp = reinterpret_cast<const float2*>(theta + 6ll * b);
    const float2 v01 = tp[0];
    const float2 v23 = tp[1];
    const float2 v45 = tp[2];
    const float thf[6] = { v01.x, v01.y, v23.x, v23.y, v45.x, v45.y };

    float st[6], ct[6];
    #pragma unroll
    for (int i = 0; i < 6; ++i)
        sincosf_deg(f_th0[i] + thf[i], &st[i], &ct[i]);

    float M[3][4];
    {
        const float ca = f_ca[0], sa = f_sa[0];
        M[0][0] = ct[0];      M[0][1] = -st[0];     M[0][2] = 0.0f; M[0][3] = f_a[0];
        M[1][0] = st[0] * ca; M[1][1] = ct[0] * ca; M[1][2] = -sa;  M[1][3] = f_nsd[0];
        M[2][0] = st[0] * sa; M[2][1] = ct[0] * sa; M[2][2] = ca;   M[2][3] = f_cd[0];
    }
    #pragma unroll
    for (int i = 1; i < 6; ++i) {
        const float ca = f_ca[i], sa = f_sa[i];
        const float t00 = ct[i],      t01 = -st[i],     t03 = f_a[i];
        const float t10 = st[i] * ca, t11 = ct[i] * ca, t12 = -sa, t13 = f_nsd[i];
        const float t20 = st[i] * sa, t21 = ct[i] * sa, t22 = ca,  t23 = f_cd[i];
        #pragma unroll
        for (int r = 0; r < 3; ++r) {
            const float m0 = M[r][0], m1 = M[r][1], m2 = M[r][2], m3 = M[r][3];
            M[r][0] = m0 * t00 + m1 * t10 + m2 * t20;
            M[r][1] = m0 * t01 + m1 * t11 + m2 * t21;
            M[r][2] =            m1 * t12 + m2 * t22;
            M[r][3] = m0 * t03 + m1 * t13 + m2 * t23 + m3;
        }
    }

    const float T00 = M[0][0], T01 = M[0][1], T02 = M[0][2];
    const float T12 = M[1][2], T22 = M[2][2];

    float ox = M[0][3], oy = M[1][3], oz = M[2][3];
    float A  = atan2f(-T01, T00) * DEG_F;
    float Bd = atan2f(T02, sqrtf(fmaf(T00, T00, T01 * T01))) * DEG_F;
    float C  = atan2f(-T12, T22) * DEG_F;

    const bool risky = (fabsf(T01) < 1e-4f) | (fabsf(T12) < 1e-4f) |
                       (fmaf(T00, T00, T01 * T01) < 1e-6f) |
                       (fmaf(T12, T12, T22 * T22) < 1e-6f);

    if (__builtin_expect(risky, 0)) {
        double dst[6], dct[6];
        #pragma unroll
        for (int i = 0; i < 6; ++i)
            sincos_deg(s_th0[i] + (double)thf[i], &dst[i], &dct[i]);

        double D[3][4];
        {
            const double ca = s_ca[0], sa = s_sa[0];
            D[0][0] = dct[0];      D[0][1] = -dst[0];     D[0][2] = 0.0; D[0][3] = s_a[0];
            D[1][0] = dst[0] * ca; D[1][1] = dct[0] * ca; D[1][2] = -sa; D[1][3] = s_nsd[0];
            D[2][0] = dst[0] * sa; D[2][1] = dct[0] * sa; D[2][2] = ca;  D[2][3] = s_cd[0];
        }
        #pragma unroll
        for (int i = 1; i < 6; ++i) {
            const double ca = s_ca[i], sa = s_sa[i];
            const double t00 = dct[i],      t01 = -dst[i],     t03 = s_a[i];
            const double t10 = dst[i] * ca, t11 = dct[i] * ca, t12 = -sa, t13 = s_nsd[i];
            const double t20 = dst[i] * sa, t21 = dct[i] * sa, t22 = ca,  t23 = s_cd[i];
            #pragma unroll
            for (int r = 0; r < 3; ++r) {
                const double m0 = D[r][0], m1 = D[r][1], m2 = D[r][2], m3 = D[r][3];
                D[r][0] = m0 * t00 + m1 * t10 + m2 * t20;
                D[r][1] = m0 * t01 + m1 * t11 + m2 * t21;
                D[r][2] =            m1 * t12 + m2 * t22;
                D[r][3] = m0 * t03 + m1 * t13 + m2 * t23 + m3;
            }
        }
        const float d00 = (float)D[0][0], d01 = (float)D[0][1], d02 = (float)D[0][2];
        const float d12 = (float)D[1][2], d22 = (float)D[2][2];

        ox = (float)D[0][3]; oy = (float)D[1][3]; oz = (float)D[2][3];
        A  = atan2f(-d01, d00) * DEG_F;
        Bd = atan2f(d02, sqrtf(fmaf(d00, d00, d01 * d01))) * DEG_F;
        C  = atan2f(-d12, d22) * DEG_F;
        if (fabs(D[1][2]) <= TINY_D && fabs(D[2][2]) <= TINY_D) {
            Bd = atan2f(d02, d22) * DEG_F;
            A  = atan2f((float)D[1][0], (float)D[1][1]) * DEG_F;
            C  = 0.0f;
        }
    }

    float2* op = reinterpret_cast<float2*>(out + 6ll * b);
    op[0] = make_float2(ox, oy);
    op[1] = make_float2(oz, A);
    op[2] = make_float2(Bd, C);
}

extern "C" void kernel_launch(void* const* d_in, const int* in_sizes, int n_in,
                              void* d_out, int out_size, void* d_ws, size_t ws_size,
                              hipStream_t stream) {
    const float* theta = (const float*)d_in[0];   // (B, 6) f32
    const float* dh    = (const float*)d_in[1];   // (6, 4) f32
    float* out = (float*)d_out;                   // (B, 6) f32

    const int B = in_sizes[0] / 6;
    const int block = 256;
    const int grid = (B + block - 1) / block;

    if (ws_size >= 65536) {
        unsigned* risk_cnt = (unsigned*)d_ws;
        unsigned* risk_idx = (unsigned*)((char*)d_ws + 256);
        const unsigned cap = (unsigned)((ws_size - 256) / 4);
        hipMemsetAsync(d_ws, 0, 4, stream);   // zero the counter (capturable)
        fk6_fast<<<grid, block, 0, stream>>>(theta, dh, out,
                                             risk_cnt, risk_idx, cap, B);
        fk6_fix<<<16, 256, 0, stream>>>(theta, dh, out, risk_cnt, risk_idx, cap);
    } else {
        fk6_combined<<<grid, block, 0, stream>>>(theta, dh, out, B);
    }
}

// Round 8
// 34.258 us; speedup vs baseline: 1.8949x; 1.0030x over previous
//
#include <hip/hip_runtime.h>
#include <math.h>

// Forward kinematics, 6-joint DH chain, B=1048576.
// R8: two-kernel split with NO memset and NO global atomic.
//   fk6_fast : pure-f32 chain. Each block collects its risky lanes in LDS and
//              ALWAYS writes its count (0 included) to counts[blockIdx] plus
//              up to RISK_CAP indices to its own slot -> no ws init needed.
//              (R7 lesson: hipMemsetAsync in a captured graph = ~41us/replay.)
//   fk6_fix  : 4096 threads grid-stride the per-block slots; recompute flagged
//              indices with the exact f64 path (slot overflow -> redo whole
//              256-element block in f64).
// Fallback: single combined kernel if ws_size is too small.

#define PI_D   3.141592653589793
#define RAD_D  (PI_D / 180.0)
#define RAD_F  0.017453292519943295f
#define DEG_F  57.29577951308232f
#define TINY_D 1e-6
#define RISK_CAP 64u

// ---------- f64 sincos of degrees (Cephes, ~1ulp) ----------
__device__ __forceinline__ void sincos_deg(double xdeg, double* s, double* c)
{
    const double qf = rint(xdeg * (1.0 / 90.0));
    const double r  = fma(qf, -90.0, xdeg) * RAD_D;
    const int q = ((int)qf) & 3;
    const double z = r * r;

    double sp = 1.58962301576546568060e-10;
    sp = fma(sp, z, -2.50507477628578072866e-8);
    sp = fma(sp, z,  2.75573136213857245213e-6);
    sp = fma(sp, z, -1.98412698295895385996e-4);
    sp = fma(sp, z,  8.33333333332211858878e-3);
    sp = fma(sp, z, -1.66666666666666307295e-1);
    const double sr = fma(r * z, sp, r);

    double cp = -1.13585365213876817300e-11;
    cp = fma(cp, z,  2.08757008419747316778e-9);
    cp = fma(cp, z, -2.75573141792967388112e-7);
    cp = fma(cp, z,  2.48015872888517179954e-5);
    cp = fma(cp, z, -1.38888888888730564116e-3);
    cp = fma(cp, z,  4.16666666666665929218e-2);
    const double cr = fma(z * z, cp, fma(z, -0.5, 1.0));

    double ss = (q & 1) ? cr : sr;
    double cc = (q & 1) ? sr : cr;
    ss = (q & 2)       ? -ss : ss;
    cc = ((q + 1) & 2) ? -cc : cc;
    *s = ss; *c = cc;
}

// ---------- f32 sincos of degrees (Cephes f32, ~1ulp f32) ----------
__device__ __forceinline__ void sincosf_deg(float xdeg, float* s, float* c)
{
    const float qf = rintf(xdeg * (1.0f / 90.0f));
    const float r  = fmaf(qf, -90.0f, xdeg) * RAD_F;
    const int q = ((int)qf) & 3;
    const float z = r * r;

    float sp = -1.9515295891e-4f;
    sp = fmaf(sp, z,  8.3321608736e-3f);
    sp = fmaf(sp, z, -1.6666654611e-1f);
    const float sr = fmaf(r * z, sp, r);

    float cp =  2.443315711809948e-5f;
    cp = fmaf(cp, z, -1.388731625493765e-3f);
    cp = fmaf(cp, z,  4.166664568298827e-2f);
    const float cr = fmaf(z * z, cp, fmaf(z, -0.5f, 1.0f));

    float ss = (q & 1) ? cr : sr;
    float cc = (q & 1) ? sr : cr;
    ss = (q & 2)       ? -ss : ss;
    cc = ((q + 1) & 2) ? -cc : cc;
    *s = ss; *c = cc;
}

// Exact f64 recompute + store of one element (the R3-R5 validated path).
__device__ __forceinline__ void fix_one(const float* __restrict__ theta,
                                        float* __restrict__ out,
                                        const double* s_a, const double* s_ca,
                                        const double* s_sa, const double* s_nsd,
                                        const double* s_cd, const double* s_th0,
                                        long long b)
{
    const float2* tp = reinterpret_cast<const float2*>(theta + 6ll * b);
    const float2 v01 = tp[0];
    const float2 v23 = tp[1];
    const float2 v45 = tp[2];
    const double th[6] = { (double)v01.x, (double)v01.y,
                           (double)v23.x, (double)v23.y,
                           (double)v45.x, (double)v45.y };

    double dst[6], dct[6];
    #pragma unroll
    for (int i = 0; i < 6; ++i)
        sincos_deg(s_th0[i] + th[i], &dst[i], &dct[i]);

    double D[3][4];
    {
        const double ca = s_ca[0], sa = s_sa[0];
        D[0][0] = dct[0];      D[0][1] = -dst[0];     D[0][2] = 0.0; D[0][3] = s_a[0];
        D[1][0] = dst[0] * ca; D[1][1] = dct[0] * ca; D[1][2] = -sa; D[1][3] = s_nsd[0];
        D[2][0] = dst[0] * sa; D[2][1] = dct[0] * sa; D[2][2] = ca;  D[2][3] = s_cd[0];
    }
    #pragma unroll
    for (int i = 1; i < 6; ++i) {
        const double ca = s_ca[i], sa = s_sa[i];
        const double t00 = dct[i],      t01 = -dst[i],     t03 = s_a[i];
        const double t10 = dst[i] * ca, t11 = dct[i] * ca, t12 = -sa, t13 = s_nsd[i];
        const double t20 = dst[i] * sa, t21 = dct[i] * sa, t22 = ca,  t23 = s_cd[i];
        #pragma unroll
        for (int r = 0; r < 3; ++r) {
            const double m0 = D[r][0], m1 = D[r][1], m2 = D[r][2], m3 = D[r][3];
            D[r][0] = m0 * t00 + m1 * t10 + m2 * t20;
            D[r][1] = m0 * t01 + m1 * t11 + m2 * t21;
            D[r][2] =            m1 * t12 + m2 * t22;
            D[r][3] = m0 * t03 + m1 * t13 + m2 * t23 + m3;
        }
    }
    const float d00 = (float)D[0][0], d01 = (float)D[0][1], d02 = (float)D[0][2];
    const float d12 = (float)D[1][2], d22 = (float)D[2][2];

    float A  = atan2f(-d01, d00) * DEG_F;
    float Bd = atan2f(d02, sqrtf(fmaf(d00, d00, d01 * d01))) * DEG_F;
    float C  = atan2f(-d12, d22) * DEG_F;
    if (fabs(D[1][2]) <= TINY_D && fabs(D[2][2]) <= TINY_D) {
        Bd = atan2f(d02, d22) * DEG_F;
        A  = atan2f((float)D[1][0], (float)D[1][1]) * DEG_F;
        C  = 0.0f;
    }

    float2* op = reinterpret_cast<float2*>(out + 6ll * b);
    op[0] = make_float2((float)D[0][3], (float)D[1][3]);
    op[1] = make_float2((float)D[2][3], A);
    op[2] = make_float2(Bd, C);
}

// ===================== fast kernel: pure f32 =====================
__global__ __launch_bounds__(256, 4)   // <=128 VGPR cap: no spill (R6 lesson)
void fk6_fast(const float* __restrict__ theta,
              const float* __restrict__ dh,
              float* __restrict__ out,
              unsigned* __restrict__ counts,   // [gridDim.x], always written
              unsigned* __restrict__ idxs,     // [gridDim.x][RISK_CAP]
              int B)
{
    __shared__ float f_a[6], f_ca[6], f_sa[6], f_nsd[6], f_cd[6], f_th0[6];
    __shared__ unsigned s_cnt;
    __shared__ unsigned s_idx[RISK_CAP];
    if (threadIdx.x == 0) s_cnt = 0;
    if (threadIdx.x < 6) {
        const int i = threadIdx.x;
        const float a   = dh[i * 4 + 0];
        const float alp = dh[i * 4 + 1];
        const float d   = dh[i * 4 + 2];
        float sa, ca;
        sincosf_deg(alp, &sa, &ca);   // exact for multiples of 90 deg
        f_a[i] = a;  f_ca[i] = ca;  f_sa[i] = sa;
        f_nsd[i] = -sa * d;  f_cd[i] = ca * d;
        f_th0[i] = dh[i * 4 + 3];
    }
    __syncthreads();

    const long long b = (long long)blockIdx.x * blockDim.x + threadIdx.x;
    const bool valid = (b < B);

    bool risky = false;
    if (valid) {
        const float2* tp = reinterpret_cast<const float2*>(theta + 6ll * b);
        const float2 v01 = tp[0];
        const float2 v23 = tp[1];
        const float2 v45 = tp[2];
        const float thf[6] = { v01.x, v01.y, v23.x, v23.y, v45.x, v45.y };

        float st[6], ct[6];
        #pragma unroll
        for (int i = 0; i < 6; ++i)
            sincosf_deg(f_th0[i] + thf[i], &st[i], &ct[i]);

        float M[3][4];
        {
            const float ca = f_ca[0], sa = f_sa[0];
            M[0][0] = ct[0];      M[0][1] = -st[0];     M[0][2] = 0.0f; M[0][3] = f_a[0];
            M[1][0] = st[0] * ca; M[1][1] = ct[0] * ca; M[1][2] = -sa;  M[1][3] = f_nsd[0];
            M[2][0] = st[0] * sa; M[2][1] = ct[0] * sa; M[2][2] = ca;   M[2][3] = f_cd[0];
        }
        #pragma unroll
        for (int i = 1; i < 6; ++i) {
            const float ca = f_ca[i], sa = f_sa[i];
            const float t00 = ct[i],      t01 = -st[i],     t03 = f_a[i];
            const float t10 = st[i] * ca, t11 = ct[i] * ca, t12 = -sa, t13 = f_nsd[i];
            const float t20 = st[i] * sa, t21 = ct[i] * sa, t22 = ca,  t23 = f_cd[i];
            #pragma unroll
            for (int r = 0; r < 3; ++r) {
                const float m0 = M[r][0], m1 = M[r][1], m2 = M[r][2], m3 = M[r][3];
                M[r][0] = m0 * t00 + m1 * t10 + m2 * t20;
                M[r][1] = m0 * t01 + m1 * t11 + m2 * t21;
                M[r][2] =            m1 * t12 + m2 * t22;         // t02 == 0
                M[r][3] = m0 * t03 + m1 * t13 + m2 * t23 + m3;    // t33 == 1
            }
        }

        const float T00 = M[0][0], T01 = M[0][1], T02 = M[0][2];
        const float T12 = M[1][2], T22 = M[2][2];

        const float A  = atan2f(-T01, T00) * DEG_F;
        // cA*T00 - sA*T01 == sqrt(T00^2+T01^2) >= 0 -> no branch cut for B.
        const float Bd = atan2f(T02, sqrtf(fmaf(T00, T00, T01 * T01))) * DEG_F;
        const float C  = atan2f(-T12, T22) * DEG_F;

        float2* op = reinterpret_cast<float2*>(out + 6ll * b);
        op[0] = make_float2(M[0][3], M[1][3]);
        op[1] = make_float2(M[2][3], A);
        op[2] = make_float2(Bd, C);

        // Flag lanes whose sign/branch decisions sit within ~50x of f32 noise.
        risky = (fabsf(T01) < 1e-4f) | (fabsf(T12) < 1e-4f) |
                (fmaf(T00, T00, T01 * T01) < 1e-6f) |
                (fmaf(T12, T12, T22 * T22) < 1e-6f);
    }

    if (__builtin_expect(risky, 0)) {
        const unsigned pos = atomicAdd(&s_cnt, 1u);
        if (pos < RISK_CAP) s_idx[pos] = (unsigned)b;
    }
    __syncthreads();

    const unsigned cnt = s_cnt;
    if (threadIdx.x == 0) counts[blockIdx.x] = cnt;          // ALWAYS written
    if (threadIdx.x < cnt && threadIdx.x < RISK_CAP)
        idxs[blockIdx.x * RISK_CAP + threadIdx.x] = s_idx[threadIdx.x];
}

// ===================== fixup kernel: exact f64 path =====================
__global__ void fk6_fix(const float* __restrict__ theta,
                        const float* __restrict__ dh,
                        float* __restrict__ out,
                        const unsigned* __restrict__ counts,
                        const unsigned* __restrict__ idxs,
                        int nblocks)
{
    __shared__ double s_a[6], s_ca[6], s_sa[6], s_nsd[6], s_cd[6], s_th0[6];
    if (threadIdx.x < 6) {
        const int i = threadIdx.x;
        const double a   = (double)dh[i * 4 + 0];
        const double alp = (double)dh[i * 4 + 1];
        const double d   = (double)dh[i * 4 + 2];
        double sa, ca;
        sincos_deg(alp, &sa, &ca);
        s_a[i] = a;  s_ca[i] = ca;  s_sa[i] = sa;
        s_nsd[i] = -sa * d;  s_cd[i] = ca * d;
        s_th0[i] = (double)dh[i * 4 + 3];
    }
    __syncthreads();

    for (int s = blockIdx.x * blockDim.x + threadIdx.x; s < nblocks;
         s += gridDim.x * blockDim.x) {
        const unsigned cnt = counts[s];
        if (cnt == 0) continue;
        if (cnt <= RISK_CAP) {
            for (unsigned j = 0; j < cnt; ++j)
                fix_one(theta, out, s_a, s_ca, s_sa, s_nsd, s_cd, s_th0,
                        (long long)idxs[s * RISK_CAP + j]);
        } else {
            // Slot overflow (vanishingly rare): redo the whole block in f64.
            for (unsigned j = 0; j < 256; ++j)
                fix_one(theta, out, s_a, s_ca, s_sa, s_nsd, s_cd, s_th0,
                        (long long)s * 256 + j);
        }
    }
}

// ===================== fallback: combined kernel =====================
__global__ __launch_bounds__(256)
void fk6_combined(const float* __restrict__ theta,
                  const float* __restrict__ dh,
                  float* __restrict__ out,
                  int B)
{
    __shared__ double s_a[6], s_ca[6], s_sa[6], s_nsd[6], s_cd[6], s_th0[6];
    __shared__ float  f_a[6], f_ca[6], f_sa[6], f_nsd[6], f_cd[6], f_th0[6];
    if (threadIdx.x < 6) {
        const int i = threadIdx.x;
        const double a   = (double)dh[i * 4 + 0];
        const double alp = (double)dh[i * 4 + 1];
        const double d   = (double)dh[i * 4 + 2];
        const double th0 = (double)dh[i * 4 + 3];
        double sa, ca;
        sincos_deg(alp, &sa, &ca);
        s_a[i] = a;  s_ca[i] = ca;  s_sa[i] = sa;
        s_nsd[i] = -sa * d;  s_cd[i] = ca * d;  s_th0[i] = th0;
        f_a[i] = (float)a;  f_ca[i] = (float)ca;  f_sa[i] = (float)sa;
        f_nsd[i] = (float)(-sa * d);  f_cd[i] = (float)(ca * d);  f_th0[i] = (float)th0;
    }
    __syncthreads();

    const long long b = (long long)blockIdx.x * blockDim.x + threadIdx.x;
    if (b >= B) return;

    const float2* tp = reinterpret_cast<const float2*>(theta + 6ll * b);
    const float2 v01 = tp[0];
    const float2 v23 = tp[1];
    const float2 v45 = tp[2];
    const float thf[6] = { v01.x, v01.y, v23.x, v23.y, v45.x, v45.y };

    float st[6], ct[6];
    #pragma unroll
    for (int i = 0; i < 6; ++i)
        sincosf_deg(f_th0[i] + thf[i], &st[i], &ct[i]);

    float M[3][4];
    {
        const float ca = f_ca[0], sa = f_sa[0];
        M[0][0] = ct[0];      M[0][1] = -st[0];     M[0][2] = 0.0f; M[0][3] = f_a[0];
        M[1][0] = st[0] * ca; M[1][1] = ct[0] * ca; M[1][2] = -sa;  M[1][3] = f_nsd[0];
        M[2][0] = st[0] * sa; M[2][1] = ct[0] * sa; M[2][2] = ca;   M[2][3] = f_cd[0];
    }
    #pragma unroll
    for (int i = 1; i < 6; ++i) {
        const float ca = f_ca[i], sa = f_sa[i];
        const float t00 = ct[i],      t01 = -st[i],     t03 = f_a[i];
        const float t10 = st[i] * ca, t11 = ct[i] * ca, t12 = -sa, t13 = f_nsd[i];
        const float t20 = st[i] * sa, t21 = ct[i] * sa, t22 = ca,  t23 = f_cd[i];
        #pragma unroll
        for (int r = 0; r < 3; ++r) {
            const float m0 = M[r][0], m1 = M[r][1], m2 = M[r][2], m3 = M[r][3];
            M[r][0] = m0 * t00 + m1 * t10 + m2 * t20;
            M[r][1] = m0 * t01 + m1 * t11 + m2 * t21;
            M[r][2] =            m1 * t12 + m2 * t22;
            M[r][3] = m0 * t03 + m1 * t13 + m2 * t23 + m3;
        }
    }

    const float T00 = M[0][0], T01 = M[0][1], T02 = M[0][2];
    const float T12 = M[1][2], T22 = M[2][2];

    float ox = M[0][3], oy = M[1][3], oz = M[2][3];
    float A  = atan2f(-T01, T00) * DEG_F;
    float Bd = atan2f(T02, sqrtf(fmaf(T00, T00, T01 * T01))) * DEG_F;
    float C  = atan2f(-T12, T22) * DEG_F;

    const bool risky = (fabsf(T01) < 1e-4f) | (fabsf(T12) < 1e-4f) |
                       (fmaf(T00, T00, T01 * T01) < 1e-6f) |
                       (fmaf(T12, T12, T22 * T22) < 1e-6f);

    if (__builtin_expect(risky, 0)) {
        double dst[6], dct[6];
        #pragma unroll
        for (int i = 0; i < 6; ++i)
            sincos_deg(s_th0[i] + (double)thf[i], &dst[i], &dct[i]);

        double D[3][4];
        {
            const double ca = s_ca[0], sa = s_sa[0];
            D[0][0] = dct[0];      D[0][1] = -dst[0];     D[0][2] = 0.0; D[0][3] = s_a[0];
            D[1][0] = dst[0] * ca; D[1][1] = dct[0] * ca; D[1][2] = -sa; D[1][3] = s_nsd[0];
            D[2][0] = dst[0] * sa; D[2][1] = dct[0] * sa; D[2][2] = ca;  D[2][3] = s_cd[0];
        }
        #pragma unroll
        for (int i = 1; i < 6; ++i) {
            const double ca = s_ca[i], sa = s_sa[i];
            const double t00 = dct[i],      t01 = -dst[i],     t03 = s_a[i];
            const double t10 = dst[i] * ca, t11 = dct[i] * ca, t12 = -sa, t13 = s_nsd[i];
            const double t20 = dst[i] * sa, t21 = dct[i] * sa, t22 = ca,  t23 = s_cd[i];
            #pragma unroll
            for (int r = 0; r < 3; ++r) {
                const double m0 = D[r][0], m1 = D[r][1], m2 = D[r][2], m3 = D[r][3];
                D[r][0] = m0 * t00 + m1 * t10 + m2 * t20;
                D[r][1] = m0 * t01 + m1 * t11 + m2 * t21;
                D[r][2] =            m1 * t12 + m2 * t22;
                D[r][3] = m0 * t03 + m1 * t13 + m2 * t23 + m3;
            }
        }
        const float d00 = (float)D[0][0], d01 = (float)D[0][1], d02 = (float)D[0][2];
        const float d12 = (float)D[1][2], d22 = (float)D[2][2];

        ox = (float)D[0][3]; oy = (float)D[1][3]; oz = (float)D[2][3];
        A  = atan2f(-d01, d00) * DEG_F;
        Bd = atan2f(d02, sqrtf(fmaf(d00, d00, d01 * d01))) * DEG_F;
        C  = atan2f(-d12, d22) * DEG_F;
        if (fabs(D[1][2]) <= TINY_D && fabs(D[2][2]) <= TINY_D) {
            Bd = atan2f(d02, d22) * DEG_F;
            A  = atan2f((float)D[1][0], (float)D[1][1]) * DEG_F;
            C  = 0.0f;
        }
    }

    float2* op = reinterpret_cast<float2*>(out + 6ll * b);
    op[0] = make_float2(ox, oy);
    op[1] = make_float2(oz, A);
    op[2] = make_float2(Bd, C);
}

extern "C" void kernel_launch(void* const* d_in, const int* in_sizes, int n_in,
                              void* d_out, int out_size, void* d_ws, size_t ws_size,
                              hipStream_t stream) {
    const float* theta = (const float*)d_in[0];   // (B, 6) f32
    const float* dh    = (const float*)d_in[1];   // (6, 4) f32
    float* out = (float*)d_out;                   // (B, 6) f32

    const int B = in_sizes[0] / 6;
    const int block = 256;
    const int grid = (B + block - 1) / block;

    // ws layout: counts[grid] (u32) | idxs[grid][RISK_CAP] (u32)
    const size_t need = (size_t)grid * 4 + (size_t)grid * RISK_CAP * 4;
    if (ws_size >= need) {
        unsigned* counts = (unsigned*)d_ws;
        unsigned* idxs   = counts + grid;
        fk6_fast<<<grid, block, 0, stream>>>(theta, dh, out, counts, idxs, B);
        fk6_fix<<<16, 256, 0, stream>>>(theta, dh, out, counts, idxs, grid);
    } else {
        fk6_combined<<<grid, block, 0, stream>>>(theta, dh, out, B);
    }
}